// Round 2
// baseline (331.919 us; speedup 1.0000x reference)
//
#include <hip/hip_runtime.h>
#include <hip/hip_bf16.h>

#define S_LEN 2048
#define DH 64
#define QBLK 128
#define KVBLK 64
#define LDP 72   // padded row length (bf16): rows stay 16B-aligned (144B), bank stride 36%32=4

typedef __attribute__((ext_vector_type(4))) float f32x4;
typedef __attribute__((ext_vector_type(8))) short short8v;
typedef __attribute__((ext_vector_type(4))) short short4v;

__device__ __forceinline__ short f2bf(float f) {
    unsigned u = __builtin_bit_cast(unsigned, f);
    u = (u + 0x7fffu + ((u >> 16) & 1u)) >> 16;
    return (short)u;
}

__global__ __launch_bounds__(256, 4) void fa_fwd_kernel(
    const float* __restrict__ Q, const float* __restrict__ K,
    const float* __restrict__ V, float* __restrict__ O)
{
    const int tid  = threadIdx.x;
    const int lane = tid & 63;
    const int w    = tid >> 6;
    // LPT ordering: heavy q-tiles (large qb => many KV iters) dispatch FIRST.
    const int bh   = blockIdx.x & 63;          // all 64 (b,h) adjacent -> spread over CUs
    const int qb   = 15 - (blockIdx.x >> 6);   // qb descending

    const size_t base = (size_t)bh * S_LEN * DH;
    const float* Qg = Q + base;
    const float* Kg = K + base;
    const float* Vg = V + base;
    float*       Og = O + base;

    __shared__ short K_lds[KVBLK][LDP];     // [kv][d]
    __shared__ short V_lds[DH][LDP];        // transposed: [d][kv]
    __shared__ short P_lds[4][32][LDP];     // per-wave [row][kv]

    const int lr = lane & 15;   // 0..15
    const int lg = lane >> 4;   // 0..3

    // ---- hoist Q fragments; fold softmax scale AND log2(e) (exp2 domain) ----
    const float qscale = 0.125f * 1.44269504088896340736f;
    const int q0 = qb * QBLK + w * 32;
    short8v qfrag[2][2];
    #pragma unroll
    for (int rt = 0; rt < 2; ++rt) {
        #pragma unroll
        for (int kf = 0; kf < 2; ++kf) {
            const float* qp = Qg + (size_t)(q0 + rt * 16 + lr) * DH + kf * 32 + lg * 8;
            f32x4 a = *(const f32x4*)qp;
            f32x4 b = *(const f32x4*)(qp + 4);
            short8v f;
            f[0] = f2bf(a[0] * qscale); f[1] = f2bf(a[1] * qscale);
            f[2] = f2bf(a[2] * qscale); f[3] = f2bf(a[3] * qscale);
            f[4] = f2bf(b[0] * qscale); f[5] = f2bf(b[1] * qscale);
            f[6] = f2bf(b[2] * qscale); f[7] = f2bf(b[3] * qscale);
            qfrag[rt][kf] = f;
        }
    }

    f32x4 o_acc[2][4];
    float m_run[2][4], l_run[2][4];
    #pragma unroll
    for (int rt = 0; rt < 2; ++rt)
        #pragma unroll
        for (int i = 0; i < 4; ++i) {
            o_acc[rt][i] = (f32x4){0.f, 0.f, 0.f, 0.f};
            m_run[rt][i] = -1e30f;
            l_run[rt][i] = 0.f;
        }

    // ---- register prefetch buffers (bf16-packed at load: +16 VGPR) ----
    short4v  kpf[4];
    unsigned vpf[8];
    const int vd  = tid & 63;
    const int vg4 = tid >> 6;

    auto prefetch = [&](int kvb) {
        #pragma unroll
        for (int i = 0; i < 4; ++i) {
            int id = i * 256 + tid;
            int kr = id >> 4;
            int dc = (id & 15) * 4;
            f32x4 vv = *(const f32x4*)(Kg + (size_t)(kvb + kr) * DH + dc);
            short4v s4;
            s4[0] = f2bf(vv[0]); s4[1] = f2bf(vv[1]);
            s4[2] = f2bf(vv[2]); s4[3] = f2bf(vv[3]);
            kpf[i] = s4;
        }
        #pragma unroll
        for (int i = 0; i < 8; ++i) {
            int kv = vg4 * 16 + i * 2;
            float a = Vg[(size_t)(kvb + kv) * DH + vd];
            float b = Vg[(size_t)(kvb + kv + 1) * DH + vd];
            vpf[i] = (unsigned)(unsigned short)f2bf(a) |
                     ((unsigned)(unsigned short)f2bf(b) << 16);
        }
    };

    const int kv_end = (qb + 1) * QBLK;   // causal extent for this q-block

    prefetch(0);

    for (int kvb = 0; kvb < kv_end; kvb += KVBLK) {
        __syncthreads();   // previous iteration's LDS readers done

        // ---- write prefetched tile to LDS ----
        #pragma unroll
        for (int i = 0; i < 4; ++i) {
            int id = i * 256 + tid;
            int kr = id >> 4;
            int dc = (id & 15) * 4;
            *(short4v*)&K_lds[kr][dc] = kpf[i];
        }
        #pragma unroll
        for (int i = 0; i < 8; ++i) {
            int kv = vg4 * 16 + i * 2;
            *(unsigned*)((char*)&V_lds[0][0] + vd * (LDP * 2) + kv * 2) = vpf[i];
        }
        __syncthreads();

        // ---- issue next tile's global loads NOW; they land during compute ----
        if (kvb + KVBLK < kv_end) prefetch(kvb + KVBLK);

        // ---- QK^T ----
        f32x4 s_acc[2][4];
        #pragma unroll
        for (int rt = 0; rt < 2; ++rt)
            #pragma unroll
            for (int kt = 0; kt < 4; ++kt)
                s_acc[rt][kt] = (f32x4){0.f, 0.f, 0.f, 0.f};

        #pragma unroll
        for (int kt = 0; kt < 4; ++kt) {
            short8v kf0 = *(const short8v*)&K_lds[kt * 16 + lr][lg * 8];
            short8v kf1 = *(const short8v*)&K_lds[kt * 16 + lr][32 + lg * 8];
            #pragma unroll
            for (int rt = 0; rt < 2; ++rt) {
                s_acc[rt][kt] = __builtin_amdgcn_mfma_f32_16x16x32_bf16(
                    qfrag[rt][0], kf0, s_acc[rt][kt], 0, 0, 0);
                s_acc[rt][kt] = __builtin_amdgcn_mfma_f32_16x16x32_bf16(
                    qfrag[rt][1], kf1, s_acc[rt][kt], 0, 0, 0);
            }
        }

        // ---- mask (diagonal tiles only) + online softmax (exp2 domain) ----
        const bool needmask = (kvb + KVBLK - 1) > q0;
        #pragma unroll
        for (int rt = 0; rt < 2; ++rt) {
            #pragma unroll
            for (int r = 0; r < 4; ++r) {
                const int qrow = q0 + rt * 16 + lg * 4 + r;
                if (needmask) {
                    #pragma unroll
                    for (int kt = 0; kt < 4; ++kt) {
                        int kvv = kvb + kt * 16 + lr;
                        if (kvv > qrow) s_acc[rt][kt][r] = -1e30f;
                    }
                }
                float tmax = fmaxf(fmaxf(s_acc[rt][0][r], s_acc[rt][1][r]),
                                   fmaxf(s_acc[rt][2][r], s_acc[rt][3][r]));
                tmax = fmaxf(tmax, __shfl_xor(tmax, 1));
                tmax = fmaxf(tmax, __shfl_xor(tmax, 2));
                tmax = fmaxf(tmax, __shfl_xor(tmax, 4));
                tmax = fmaxf(tmax, __shfl_xor(tmax, 8));
                float mnew = fmaxf(m_run[rt][r], tmax);
                float corr = exp2f(m_run[rt][r] - mnew);
                m_run[rt][r] = mnew;
                float rsum = 0.f;
                #pragma unroll
                for (int kt = 0; kt < 4; ++kt) {
                    float p = exp2f(s_acc[rt][kt][r] - mnew);
                    s_acc[rt][kt][r] = p;
                    rsum += p;
                }
                rsum += __shfl_xor(rsum, 1);
                rsum += __shfl_xor(rsum, 2);
                rsum += __shfl_xor(rsum, 4);
                rsum += __shfl_xor(rsum, 8);
                l_run[rt][r] = l_run[rt][r] * corr + rsum;
                #pragma unroll
                for (int dt = 0; dt < 4; ++dt)
                    o_acc[rt][dt][r] *= corr;
            }
        }

        // ---- P -> LDS (wave-private), then PV MFMAs ----
        #pragma unroll
        for (int rt = 0; rt < 2; ++rt)
            #pragma unroll
            for (int kt = 0; kt < 4; ++kt)
                #pragma unroll
                for (int r = 0; r < 4; ++r)
                    P_lds[w][rt * 16 + lg * 4 + r][kt * 16 + lr] = f2bf(s_acc[rt][kt][r]);

        short8v pfrag[2][2];
        #pragma unroll
        for (int rt = 0; rt < 2; ++rt)
            #pragma unroll
            for (int kf = 0; kf < 2; ++kf)
                pfrag[rt][kf] = *(const short8v*)&P_lds[w][rt * 16 + lr][kf * 32 + lg * 8];

        #pragma unroll
        for (int dt = 0; dt < 4; ++dt) {
            const char* vb = (const char*)&V_lds[0][0] + (dt * 16 + lr) * (LDP * 2);
            short8v v0 = *(const short8v*)(vb + (lg * 8) * 2);
            short8v v1 = *(const short8v*)(vb + (32 + lg * 8) * 2);
            #pragma unroll
            for (int rt = 0; rt < 2; ++rt) {
                o_acc[rt][dt] = __builtin_amdgcn_mfma_f32_16x16x32_bf16(
                    pfrag[rt][0], v0, o_acc[rt][dt], 0, 0, 0);
                o_acc[rt][dt] = __builtin_amdgcn_mfma_f32_16x16x32_bf16(
                    pfrag[rt][1], v1, o_acc[rt][dt], 0, 0, 0);
            }
        }
    }

    // ---- epilogue: divide by l, write fp32 ----
    #pragma unroll
    for (int rt = 0; rt < 2; ++rt) {
        #pragma unroll
        for (int r = 0; r < 4; ++r) {
            float inv = 1.0f / l_run[rt][r];
            int qrow = q0 + rt * 16 + lg * 4 + r;
            float* op = Og + (size_t)qrow * DH + lr;
            #pragma unroll
            for (int dt = 0; dt < 4; ++dt)
                op[dt * 16] = o_acc[rt][dt][r] * inv;
        }
    }
}

extern "C" void kernel_launch(void* const* d_in, const int* in_sizes, int n_in,
                              void* d_out, int out_size, void* d_ws, size_t ws_size,
                              hipStream_t stream) {
    const float* q = (const float*)d_in[0];
    const float* k = (const float*)d_in[1];
    const float* v = (const float*)d_in[2];
    float* out = (float*)d_out;
    fa_fwd_kernel<<<dim3(1024), dim3(256), 0, stream>>>(q, k, v, out);
}

// Round 3
// 121.298 us; speedup vs baseline: 2.7364x; 2.7364x over previous
//
#include <hip/hip_runtime.h>
#include <hip/hip_bf16.h>

#define S_LEN 2048
#define DH 64
#define QBLK 128
#define KVBLK 64
#define LDPK 72   // K rows: 144B (16B-aligned for b128), bank stride 36%32=4 -> 2-way (free)
#define LDPV 68   // V^T rows: 136B (8B-aligned for b64), bank stride 34%32=2 -> 4-way writes

typedef __attribute__((ext_vector_type(4))) float f32x4;
typedef __attribute__((ext_vector_type(8))) short short8v;
typedef __attribute__((ext_vector_type(4))) short short4v;

__device__ __forceinline__ short f2bf(float f) {
    unsigned u = __builtin_bit_cast(unsigned, f);
    u = (u + 0x7fffu + ((u >> 16) & 1u)) >> 16;
    return (short)u;
}

__global__ __launch_bounds__(256) void fa_fwd_kernel(
    const float* __restrict__ Q, const float* __restrict__ K,
    const float* __restrict__ V, float* __restrict__ O)
{
    const int tid  = threadIdx.x;
    const int lane = tid & 63;
    const int w    = tid >> 6;
    // LPT: heavy q-tiles (large qb) first; all 64 (b,h) adjacent.
    const int bh   = blockIdx.x & 63;
    const int qb   = 15 - (blockIdx.x >> 6);

    const size_t base = (size_t)bh * S_LEN * DH;
    const float* Qg = Q + base;
    const float* Kg = K + base;
    const float* Vg = V + base;
    float*       Og = O + base;

    __shared__ short K_lds[KVBLK][LDPK];   // [kv][d]
    __shared__ short V_lds[DH][LDPV];      // transposed: [d][kv]

    const int lr = lane & 15;   // 0..15
    const int lg = lane >> 4;   // 0..3

    // ---- hoist Q fragments; fold softmax scale and log2(e) ----
    const float qscale = 0.125f * 1.44269504088896340736f;
    const int q0 = qb * QBLK + w * 32;
    short8v qfrag[2][2];
    #pragma unroll
    for (int rt = 0; rt < 2; ++rt) {
        #pragma unroll
        for (int kf = 0; kf < 2; ++kf) {
            const float* qp = Qg + (size_t)(q0 + rt * 16 + lr) * DH + kf * 32 + lg * 8;
            f32x4 a = *(const f32x4*)qp;
            f32x4 b = *(const f32x4*)(qp + 4);
            short8v f;
            f[0] = f2bf(a[0] * qscale); f[1] = f2bf(a[1] * qscale);
            f[2] = f2bf(a[2] * qscale); f[3] = f2bf(a[3] * qscale);
            f[4] = f2bf(b[0] * qscale); f[5] = f2bf(b[1] * qscale);
            f[6] = f2bf(b[2] * qscale); f[7] = f2bf(b[3] * qscale);
            qfrag[rt][kf] = f;
        }
    }

    f32x4 o_acc[2][4];
    float m_run[2], l_run[2];
    #pragma unroll
    for (int rt = 0; rt < 2; ++rt) {
        #pragma unroll
        for (int i = 0; i < 4; ++i)
            o_acc[rt][i] = (f32x4){0.f, 0.f, 0.f, 0.f};
        m_run[rt] = -1e30f;
        l_run[rt] = 0.f;
    }

    // ---- register prefetch buffers (bf16-packed at load) ----
    short4v  kpf[4];
    unsigned vpf[8];
    const int vd  = tid & 63;
    const int vg4 = tid >> 6;

    const int kv_end = (qb + 1) * QBLK;

    // initial prefetch (kvb = 0)
    #pragma unroll
    for (int i = 0; i < 4; ++i) {
        int id = i * 256 + tid;
        int kr = id >> 4;
        int dc = (id & 15) * 4;
        f32x4 vv = *(const f32x4*)(Kg + (size_t)kr * DH + dc);
        short4v s4;
        s4[0] = f2bf(vv[0]); s4[1] = f2bf(vv[1]);
        s4[2] = f2bf(vv[2]); s4[3] = f2bf(vv[3]);
        kpf[i] = s4;
    }
    #pragma unroll
    for (int i = 0; i < 8; ++i) {
        int kv = vg4 * 16 + i * 2;
        float a = Vg[(size_t)kv * DH + vd];
        float b = Vg[(size_t)(kv + 1) * DH + vd];
        vpf[i] = (unsigned)(unsigned short)f2bf(a) |
                 ((unsigned)(unsigned short)f2bf(b) << 16);
    }

    for (int kvb = 0; kvb < kv_end; kvb += KVBLK) {
        __syncthreads();   // previous iteration's LDS readers done

        // ---- write prefetched tile to LDS ----
        #pragma unroll
        for (int i = 0; i < 4; ++i) {
            int id = i * 256 + tid;
            int kr = id >> 4;
            int dc = (id & 15) * 4;
            *(short4v*)&K_lds[kr][dc] = kpf[i];
        }
        #pragma unroll
        for (int i = 0; i < 8; ++i) {
            int kv = vg4 * 16 + i * 2;
            *(unsigned*)((char*)&V_lds[0][0] + vd * (LDPV * 2) + kv * 2) = vpf[i];
        }
        __syncthreads();

        // ---- issue next tile's global loads; they land under compute ----
        if (kvb + KVBLK < kv_end) {
            const int nb = kvb + KVBLK;
            #pragma unroll
            for (int i = 0; i < 4; ++i) {
                int id = i * 256 + tid;
                int kr = id >> 4;
                int dc = (id & 15) * 4;
                f32x4 vv = *(const f32x4*)(Kg + (size_t)(nb + kr) * DH + dc);
                short4v s4;
                s4[0] = f2bf(vv[0]); s4[1] = f2bf(vv[1]);
                s4[2] = f2bf(vv[2]); s4[3] = f2bf(vv[3]);
                kpf[i] = s4;
            }
            #pragma unroll
            for (int i = 0; i < 8; ++i) {
                int kv = vg4 * 16 + i * 2;
                float a = Vg[(size_t)(nb + kv) * DH + vd];
                float b = Vg[(size_t)(nb + kv + 1) * DH + vd];
                vpf[i] = (unsigned)(unsigned short)f2bf(a) |
                         ((unsigned)(unsigned short)f2bf(b) << 16);
            }
        }

        // ---- swapped QK^T: S^T[kv][q] = K * Q^T  (lane: q=lr, kv=16kt+4lg+r) ----
        f32x4 s_acc[2][4];   // [rt][kt]
        #pragma unroll
        for (int rt = 0; rt < 2; ++rt)
            #pragma unroll
            for (int kt = 0; kt < 4; ++kt)
                s_acc[rt][kt] = (f32x4){0.f, 0.f, 0.f, 0.f};

        #pragma unroll
        for (int kt = 0; kt < 4; ++kt) {
            short8v kf0 = *(const short8v*)&K_lds[kt * 16 + lr][lg * 8];
            short8v kf1 = *(const short8v*)&K_lds[kt * 16 + lr][32 + lg * 8];
            #pragma unroll
            for (int rt = 0; rt < 2; ++rt) {
                s_acc[rt][kt] = __builtin_amdgcn_mfma_f32_16x16x32_bf16(
                    kf0, qfrag[rt][0], s_acc[rt][kt], 0, 0, 0);
                s_acc[rt][kt] = __builtin_amdgcn_mfma_f32_16x16x32_bf16(
                    kf1, qfrag[rt][1], s_acc[rt][kt], 0, 0, 0);
            }
        }

        // ---- mask + online softmax (q = lr per lane; kv in-register) ----
        const bool needmask = (kvb + KVBLK - 1) > q0;
        short8v pa[2][2];   // packed P fragments for PV
        #pragma unroll
        for (int rt = 0; rt < 2; ++rt) {
            const int qrow = q0 + rt * 16 + lr;
            if (needmask) {
                #pragma unroll
                for (int kt = 0; kt < 4; ++kt)
                    #pragma unroll
                    for (int r = 0; r < 4; ++r) {
                        int kvv = kvb + kt * 16 + lg * 4 + r;
                        if (kvv > qrow) s_acc[rt][kt][r] = -1e30f;
                    }
            }
            // in-lane max over 16 values, then reduce across the 4 lane-groups
            float tmax = -1e30f;
            #pragma unroll
            for (int kt = 0; kt < 4; ++kt)
                #pragma unroll
                for (int r = 0; r < 4; ++r)
                    tmax = fmaxf(tmax, s_acc[rt][kt][r]);
            tmax = fmaxf(tmax, __shfl_xor(tmax, 16));
            tmax = fmaxf(tmax, __shfl_xor(tmax, 32));
            float mnew = fmaxf(m_run[rt], tmax);
            float corr = exp2f(m_run[rt] - mnew);
            m_run[rt] = mnew;
            float rsum = 0.f;
            #pragma unroll
            for (int kt = 0; kt < 4; ++kt)
                #pragma unroll
                for (int r = 0; r < 4; ++r) {
                    float p = exp2f(s_acc[rt][kt][r] - mnew);
                    s_acc[rt][kt][r] = p;
                    rsum += p;
                }
            rsum += __shfl_xor(rsum, 16);
            rsum += __shfl_xor(rsum, 32);
            l_run[rt] = l_run[rt] * corr + rsum;

            // pack P into A-fragments with k-order kappa(lg,j):
            //   j<4 -> kv = 16*(2kf) + 4lg + j ; j>=4 -> kv = 16*(2kf+1) + 4lg + (j-4)
            #pragma unroll
            for (int kf = 0; kf < 2; ++kf) {
                short8v f;
                #pragma unroll
                for (int r = 0; r < 4; ++r) {
                    f[r]     = f2bf(s_acc[rt][2 * kf][r]);
                    f[r + 4] = f2bf(s_acc[rt][2 * kf + 1][r]);
                }
                pa[rt][kf] = f;
            }

            // rescale o_acc: lane's o-rows are q = 4lg+r -> fetch corr from lane 4lg+r
            #pragma unroll
            for (int r = 0; r < 4; ++r) {
                float c = __shfl(corr, 4 * lg + r);
                #pragma unroll
                for (int dt = 0; dt < 4; ++dt)
                    o_acc[rt][dt][r] *= c;
            }
        }

        // ---- PV: B-frags from V^T with matching kappa ordering ----
        #pragma unroll
        for (int dt = 0; dt < 4; ++dt) {
            const char* vrow = (const char*)&V_lds[0][0] + (dt * 16 + lr) * (LDPV * 2);
            #pragma unroll
            for (int kf = 0; kf < 2; ++kf) {
                short4v vlo = *(const short4v*)(vrow + (kf * 32 + 4 * lg) * 2);
                short4v vhi = *(const short4v*)(vrow + (kf * 32 + 16 + 4 * lg) * 2);
                short8v vv;
                vv[0] = vlo[0]; vv[1] = vlo[1]; vv[2] = vlo[2]; vv[3] = vlo[3];
                vv[4] = vhi[0]; vv[5] = vhi[1]; vv[6] = vhi[2]; vv[7] = vhi[3];
                #pragma unroll
                for (int rt = 0; rt < 2; ++rt)
                    o_acc[rt][dt] = __builtin_amdgcn_mfma_f32_16x16x32_bf16(
                        pa[rt][kf], vv, o_acc[rt][dt], 0, 0, 0);
            }
        }
    }

    // ---- epilogue: divide by l (fetched from lane 4lg+r), write fp32 ----
    #pragma unroll
    for (int rt = 0; rt < 2; ++rt) {
        #pragma unroll
        for (int r = 0; r < 4; ++r) {
            float lsum = __shfl(l_run[rt], 4 * lg + r);
            float inv = 1.0f / lsum;
            int qrow = q0 + rt * 16 + lg * 4 + r;
            float* op = Og + (size_t)qrow * DH + lr;
            #pragma unroll
            for (int dt = 0; dt < 4; ++dt)
                op[dt * 16] = o_acc[rt][dt][r] * inv;
        }
    }
}

extern "C" void kernel_launch(void* const* d_in, const int* in_sizes, int n_in,
                              void* d_out, int out_size, void* d_ws, size_t ws_size,
                              hipStream_t stream) {
    const float* q = (const float*)d_in[0];
    const float* k = (const float*)d_in[1];
    const float* v = (const float*)d_in[2];
    float* out = (float*)d_out;
    fa_fwd_kernel<<<dim3(1024), dim3(256), 0, stream>>>(q, k, v, out);
}

// Round 4
// 94.228 us; speedup vs baseline: 3.5225x; 1.2873x over previous
//
#include <hip/hip_runtime.h>
#include <hip/hip_bf16.h>

#define S_LEN 2048
#define DH 64
#define QBLK 128
#define KVBLK 64
#define LDPK 72   // K rows: 144B (16B-aligned), bank stride 36%32=4
#define LDPV 68   // V^T rows: 136B (8B-aligned), bank stride 34%32=2

typedef __attribute__((ext_vector_type(4))) float f32x4;
typedef __attribute__((ext_vector_type(8))) short short8v;
typedef __attribute__((ext_vector_type(4))) unsigned uint4v;

__device__ __forceinline__ unsigned cvt_pk(float a, float b) {
    unsigned r;
    asm("v_cvt_pk_bf16_f32 %0, %1, %2" : "=v"(r) : "v"(a), "v"(b));
    return r;
}

__global__ __launch_bounds__(256) void fa_fwd_kernel(
    const float* __restrict__ Q, const float* __restrict__ K,
    const float* __restrict__ V, float* __restrict__ O)
{
    const int tid  = threadIdx.x;
    const int lane = tid & 63;
    const int w    = tid >> 6;
    // uniform-cost blocks: each handles q-tiles {15-p, p} -> 34 KV-iters for every block
    const int bh   = blockIdx.x & 63;
    const int p    = blockIdx.x >> 6;   // 0..7

    const size_t base = (size_t)bh * S_LEN * DH;
    const float* Qg = Q + base;
    const float* Kg = K + base;
    const float* Vg = V + base;
    float*       Og = O + base;

    __shared__ __align__(16) short K_lds[KVBLK][LDPK];   // [kv][d]
    __shared__ __align__(16) short V_lds[DH][LDPV];      // transposed: [d][kv]

    const int lr = lane & 15;
    const int lg = lane >> 4;
    const int vd  = tid & 63;
    const int vg4 = tid >> 6;

    // ---- register prefetch buffers (bf16-packed at load) ----
    unsigned kpfu[8];
    unsigned vpf[8];

    auto prefetch = [&](int kvb) {
        #pragma unroll
        for (int i = 0; i < 2; ++i) {
            int id = i * 256 + tid;
            int kr = id >> 3;             // row 0..63
            int dc = (id & 7) * 8;        // col 0,8,...,56
            const float* kp = Kg + (size_t)(kvb + kr) * DH + dc;
            f32x4 a = *(const f32x4*)kp;
            f32x4 b = *(const f32x4*)(kp + 4);
            kpfu[4 * i + 0] = cvt_pk(a[0], a[1]);
            kpfu[4 * i + 1] = cvt_pk(a[2], a[3]);
            kpfu[4 * i + 2] = cvt_pk(b[0], b[1]);
            kpfu[4 * i + 3] = cvt_pk(b[2], b[3]);
        }
        #pragma unroll
        for (int i = 0; i < 8; ++i) {
            int kv = vg4 * 16 + i * 2;
            float a = Vg[(size_t)(kvb + kv) * DH + vd];
            float b = Vg[(size_t)(kvb + kv + 1) * DH + vd];
            vpf[i] = cvt_pk(a, b);
        }
    };

    auto stage = [&]() {
        #pragma unroll
        for (int i = 0; i < 2; ++i) {
            int id = i * 256 + tid;
            int kr = id >> 3;
            int dc = (id & 7) * 8;
            uint4v u = {kpfu[4 * i + 0], kpfu[4 * i + 1], kpfu[4 * i + 2], kpfu[4 * i + 3]};
            *(uint4v*)&K_lds[kr][dc] = u;   // ds_write_b128, 16B aligned
        }
        #pragma unroll
        for (int i = 0; i < 8; ++i) {
            int kv = vg4 * 16 + i * 2;
            *(unsigned*)((char*)&V_lds[0][0] + vd * (LDPV * 2) + kv * 2) = vpf[i];
        }
    };

    const float qscale = 0.125f * 1.44269504088896340736f;

    prefetch(0);

    #pragma unroll 1
    for (int t = 0; t < 2; ++t) {
        const int qb = (t == 0) ? (15 - p) : p;   // heavy tile first
        const int q0 = qb * QBLK + w * 32;
        const int kv_end = (qb + 1) * QBLK;

        // ---- Q fragments for this tile (scale + log2e folded) ----
        short8v qfrag[2][2];
        #pragma unroll
        for (int rt = 0; rt < 2; ++rt) {
            #pragma unroll
            for (int kf = 0; kf < 2; ++kf) {
                const float* qp = Qg + (size_t)(q0 + rt * 16 + lr) * DH + kf * 32 + lg * 8;
                f32x4 a = *(const f32x4*)qp;
                f32x4 b = *(const f32x4*)(qp + 4);
                uint4v u;
                u[0] = cvt_pk(a[0] * qscale, a[1] * qscale);
                u[1] = cvt_pk(a[2] * qscale, a[3] * qscale);
                u[2] = cvt_pk(b[0] * qscale, b[1] * qscale);
                u[3] = cvt_pk(b[2] * qscale, b[3] * qscale);
                qfrag[rt][kf] = __builtin_bit_cast(short8v, u);
            }
        }

        f32x4 o_acc[2][4];
        float m_run[2], l_run[2];
        #pragma unroll
        for (int rt = 0; rt < 2; ++rt) {
            #pragma unroll
            for (int i = 0; i < 4; ++i)
                o_acc[rt][i] = (f32x4){0.f, 0.f, 0.f, 0.f};
            m_run[rt] = -1e30f;
            l_run[rt] = 0.f;
        }

        for (int kvb = 0; kvb < kv_end; kvb += KVBLK) {
            __syncthreads();    // previous LDS readers done
            stage();
            __syncthreads();

            // issue next tile's global loads; they land under compute
            int nxt = kvb + KVBLK;
            if (nxt < kv_end)       prefetch(nxt);
            else if (t == 0)        prefetch(0);   // second q-tile restarts KV stream

            // ---- swapped QK^T: lane holds q=lr, kv=16kt+4lg+r ----
            f32x4 s_acc[2][4];
            #pragma unroll
            for (int rt = 0; rt < 2; ++rt)
                #pragma unroll
                for (int kt = 0; kt < 4; ++kt)
                    s_acc[rt][kt] = (f32x4){0.f, 0.f, 0.f, 0.f};

            #pragma unroll
            for (int kt = 0; kt < 4; ++kt) {
                short8v kf0 = *(const short8v*)&K_lds[kt * 16 + lr][lg * 8];
                short8v kf1 = *(const short8v*)&K_lds[kt * 16 + lr][32 + lg * 8];
                #pragma unroll
                for (int rt = 0; rt < 2; ++rt) {
                    s_acc[rt][kt] = __builtin_amdgcn_mfma_f32_16x16x32_bf16(
                        kf0, qfrag[rt][0], s_acc[rt][kt], 0, 0, 0);
                    s_acc[rt][kt] = __builtin_amdgcn_mfma_f32_16x16x32_bf16(
                        kf1, qfrag[rt][1], s_acc[rt][kt], 0, 0, 0);
                }
            }

            // ---- mask + online softmax (exp2 domain, single-inst v_exp) ----
            const bool needmask = (kvb + KVBLK - 1) > q0;
            short8v pa[2][2];
            #pragma unroll
            for (int rt = 0; rt < 2; ++rt) {
                const int qrow = q0 + rt * 16 + lr;
                if (needmask) {
                    #pragma unroll
                    for (int kt = 0; kt < 4; ++kt)
                        #pragma unroll
                        for (int r = 0; r < 4; ++r) {
                            int kvv = kvb + kt * 16 + lg * 4 + r;
                            if (kvv > qrow) s_acc[rt][kt][r] = -1e30f;
                        }
                }
                float tmax = -1e30f;
                #pragma unroll
                for (int kt = 0; kt < 4; ++kt)
                    #pragma unroll
                    for (int r = 0; r < 4; ++r)
                        tmax = fmaxf(tmax, s_acc[rt][kt][r]);
                tmax = fmaxf(tmax, __shfl_xor(tmax, 16));
                tmax = fmaxf(tmax, __shfl_xor(tmax, 32));
                float mnew = fmaxf(m_run[rt], tmax);
                float corr = __builtin_amdgcn_exp2f(m_run[rt] - mnew);
                m_run[rt] = mnew;
                float rsum = 0.f;
                #pragma unroll
                for (int kt = 0; kt < 4; ++kt)
                    #pragma unroll
                    for (int r = 0; r < 4; ++r) {
                        float pe = __builtin_amdgcn_exp2f(s_acc[rt][kt][r] - mnew);
                        s_acc[rt][kt][r] = pe;
                        rsum += pe;
                    }
                rsum += __shfl_xor(rsum, 16);
                rsum += __shfl_xor(rsum, 32);
                l_run[rt] = l_run[rt] * corr + rsum;

                // pack P into A-frags: f[r]=s[2kf][r], f[r+4]=s[2kf+1][r]
                #pragma unroll
                for (int kf = 0; kf < 2; ++kf) {
                    uint4v u;
                    u[0] = cvt_pk(s_acc[rt][2 * kf][0],     s_acc[rt][2 * kf][1]);
                    u[1] = cvt_pk(s_acc[rt][2 * kf][2],     s_acc[rt][2 * kf][3]);
                    u[2] = cvt_pk(s_acc[rt][2 * kf + 1][0], s_acc[rt][2 * kf + 1][1]);
                    u[3] = cvt_pk(s_acc[rt][2 * kf + 1][2], s_acc[rt][2 * kf + 1][3]);
                    pa[rt][kf] = __builtin_bit_cast(short8v, u);
                }

                // rescale o_acc: lane's o-rows are q = 4lg+r
                #pragma unroll
                for (int r = 0; r < 4; ++r) {
                    float c = __shfl(corr, 4 * lg + r);
                    #pragma unroll
                    for (int dt = 0; dt < 4; ++dt)
                        o_acc[rt][dt][r] *= c;
                }
            }

            // ---- PV: B-frags from V^T with matching kappa k-order ----
            #pragma unroll
            for (int dt = 0; dt < 4; ++dt) {
                const char* vrow = (const char*)&V_lds[0][0] + (dt * 16 + lr) * (LDPV * 2);
                #pragma unroll
                for (int kf = 0; kf < 2; ++kf) {
                    typedef __attribute__((ext_vector_type(2))) unsigned uint2v;
                    uint2v lo = *(const uint2v*)(vrow + (kf * 32 + 4 * lg) * 2);
                    uint2v hi = *(const uint2v*)(vrow + (kf * 32 + 16 + 4 * lg) * 2);
                    uint4v u = {lo[0], lo[1], hi[0], hi[1]};
                    short8v vv = __builtin_bit_cast(short8v, u);
                    #pragma unroll
                    for (int rt = 0; rt < 2; ++rt)
                        o_acc[rt][dt] = __builtin_amdgcn_mfma_f32_16x16x32_bf16(
                            pa[rt][kf], vv, o_acc[rt][dt], 0, 0, 0);
                }
            }
        }

        // ---- epilogue for this q-tile ----
        #pragma unroll
        for (int rt = 0; rt < 2; ++rt) {
            #pragma unroll
            for (int r = 0; r < 4; ++r) {
                float lsum = __shfl(l_run[rt], 4 * lg + r);
                float inv = 1.0f / lsum;
                int qrow = q0 + rt * 16 + lg * 4 + r;
                float* op = Og + (size_t)qrow * DH + lr;
                #pragma unroll
                for (int dt = 0; dt < 4; ++dt)
                    op[dt * 16] = o_acc[rt][dt][r] * inv;
            }
        }
    }
}

extern "C" void kernel_launch(void* const* d_in, const int* in_sizes, int n_in,
                              void* d_out, int out_size, void* d_ws, size_t ws_size,
                              hipStream_t stream) {
    const float* q = (const float*)d_in[0];
    const float* k = (const float*)d_in[1];
    const float* v = (const float*)d_in[2];
    float* out = (float*)d_out;
    // 512 uniform blocks: 64 (b,h) x 8 q-tile pairs {15-p, p}
    fa_fwd_kernel<<<dim3(512), dim3(256), 0, stream>>>(q, k, v, out);
}

// Round 5
// 79.479 us; speedup vs baseline: 4.1762x; 1.1856x over previous
//
#include <hip/hip_runtime.h>
#include <hip/hip_bf16.h>

#define S_LEN 2048
#define DH 64
#define QBLK 128
#define KVBLK 64
#define LDPK 72   // K rows: 144B (16B-aligned), bank stride 36%32=4 -> 2-way (free)
#define LDPV 68   // V^T rows: 136B (8B-aligned), bank stride 34%32=2

typedef __attribute__((ext_vector_type(4))) float f32x4;
typedef __attribute__((ext_vector_type(8))) short short8v;
typedef __attribute__((ext_vector_type(4))) unsigned uint4v;
typedef __attribute__((ext_vector_type(2))) unsigned uint2v;

__device__ __forceinline__ unsigned cvt_pk(float a, float b) {
    unsigned r;
    asm("v_cvt_pk_bf16_f32 %0, %1, %2" : "=v"(r) : "v"(a), "v"(b));
    return r;
}

__global__ __launch_bounds__(512) void fa_fwd_kernel(
    const float* __restrict__ Q, const float* __restrict__ K,
    const float* __restrict__ V, float* __restrict__ O)
{
    const int tid  = threadIdx.x;
    const int lane = tid & 63;
    const int w    = tid >> 6;          // 0..7 waves
    // uniform-cost blocks: q-tile pair {15-p, p} -> 34 KV-iters each; same-bh
    // blocks are 64 apart -> same XCD (64%8==0) -> K/V L2-resident
    const int bh   = blockIdx.x & 63;
    const int p    = blockIdx.x >> 6;   // 0..7

    const size_t base = (size_t)bh * S_LEN * DH;
    const float* Qg = Q + base;
    const float* Kg = K + base;
    const float* Vg = V + base;
    float*       Og = O + base;

    __shared__ __align__(16) short K_lds[KVBLK][LDPK];   // [kv][d]
    __shared__ __align__(16) short V_lds[DH][LDPV];      // transposed: [d][kv]

    const int lr = lane & 15;
    const int lg = lane >> 4;

    // staging decomposition (512 threads cover the 64x64 tile once)
    const int kr = tid >> 3;            // K row 0..63
    const int dc = (tid & 7) * 8;       // K col 0,8,...,56
    const int vd = tid & 63;            // V col (d)
    const int vg = tid >> 6;            // V row-group 0..7

    unsigned kpfu[4], vpf[4];

    auto prefetch = [&](int kvb) {
        const float* kp = Kg + (size_t)(kvb + kr) * DH + dc;
        f32x4 a = *(const f32x4*)kp;
        f32x4 b = *(const f32x4*)(kp + 4);
        kpfu[0] = cvt_pk(a[0], a[1]);
        kpfu[1] = cvt_pk(a[2], a[3]);
        kpfu[2] = cvt_pk(b[0], b[1]);
        kpfu[3] = cvt_pk(b[2], b[3]);
        #pragma unroll
        for (int i = 0; i < 4; ++i) {
            int kv = vg * 8 + i * 2;
            float x = Vg[(size_t)(kvb + kv) * DH + vd];
            float y = Vg[(size_t)(kvb + kv + 1) * DH + vd];
            vpf[i] = cvt_pk(x, y);
        }
    };

    auto stage = [&]() {
        uint4v u = {kpfu[0], kpfu[1], kpfu[2], kpfu[3]};
        *(uint4v*)&K_lds[kr][dc] = u;                    // ds_write_b128
        #pragma unroll
        for (int i = 0; i < 4; ++i) {
            int kv = vg * 8 + i * 2;
            *(unsigned*)((char*)&V_lds[0][0] + vd * (LDPV * 2) + kv * 2) = vpf[i];
        }
    };

    const float qscale = 0.125f * 1.44269504088896340736f;

    prefetch(0);

    #pragma unroll 1
    for (int t = 0; t < 2; ++t) {
        const int qb = (t == 0) ? (15 - p) : p;   // heavy tile first
        const int q0 = qb * QBLK + w * 16;        // this wave's 16 q-rows
        const int kv_end = (qb + 1) * QBLK;

        // ---- Q fragments (scale + log2e folded) ----
        short8v qfrag[2];
        #pragma unroll
        for (int kf = 0; kf < 2; ++kf) {
            const float* qp = Qg + (size_t)(q0 + lr) * DH + kf * 32 + lg * 8;
            f32x4 a = *(const f32x4*)qp;
            f32x4 b = *(const f32x4*)(qp + 4);
            uint4v u;
            u[0] = cvt_pk(a[0] * qscale, a[1] * qscale);
            u[1] = cvt_pk(a[2] * qscale, a[3] * qscale);
            u[2] = cvt_pk(b[0] * qscale, b[1] * qscale);
            u[3] = cvt_pk(b[2] * qscale, b[3] * qscale);
            qfrag[kf] = __builtin_bit_cast(short8v, u);
        }

        f32x4 o_acc[4];
        #pragma unroll
        for (int i = 0; i < 4; ++i)
            o_acc[i] = (f32x4){0.f, 0.f, 0.f, 0.f};
        float m_run = -1e30f, l_run = 0.f;

        for (int kvb = 0; kvb < kv_end; kvb += KVBLK) {
            __syncthreads();    // previous LDS readers done
            stage();
            __syncthreads();

            // issue next tile's global loads; they land under compute
            int nxt = kvb + KVBLK;
            if (nxt < kv_end)  prefetch(nxt);
            else if (t == 0)   prefetch(0);     // second q-tile restarts KV stream

            // fully-masked diagonal iteration for low waves: skip compute
            if (kvb <= q0 + 15) {
                // ---- swapped QK^T: lane holds q=lr, kv=16kt+4lg+r ----
                f32x4 s_acc[4];
                #pragma unroll
                for (int kt = 0; kt < 4; ++kt)
                    s_acc[kt] = (f32x4){0.f, 0.f, 0.f, 0.f};

                __builtin_amdgcn_s_setprio(1);
                #pragma unroll
                for (int kt = 0; kt < 4; ++kt) {
                    short8v kf0 = *(const short8v*)&K_lds[kt * 16 + lr][lg * 8];
                    short8v kf1 = *(const short8v*)&K_lds[kt * 16 + lr][32 + lg * 8];
                    s_acc[kt] = __builtin_amdgcn_mfma_f32_16x16x32_bf16(
                        kf0, qfrag[0], s_acc[kt], 0, 0, 0);
                    s_acc[kt] = __builtin_amdgcn_mfma_f32_16x16x32_bf16(
                        kf1, qfrag[1], s_acc[kt], 0, 0, 0);
                }
                __builtin_amdgcn_s_setprio(0);

                // ---- mask + online softmax ----
                const int qrow = q0 + lr;
                if (kvb + KVBLK - 1 > q0) {
                    #pragma unroll
                    for (int kt = 0; kt < 4; ++kt)
                        #pragma unroll
                        for (int r = 0; r < 4; ++r) {
                            int kvv = kvb + kt * 16 + lg * 4 + r;
                            if (kvv > qrow) s_acc[kt][r] = -1e30f;
                        }
                }
                float tmax = -1e30f;
                #pragma unroll
                for (int kt = 0; kt < 4; ++kt)
                    #pragma unroll
                    for (int r = 0; r < 4; ++r)
                        tmax = fmaxf(tmax, s_acc[kt][r]);
                tmax = fmaxf(tmax, __shfl_xor(tmax, 16));
                tmax = fmaxf(tmax, __shfl_xor(tmax, 32));
                float mnew = fmaxf(m_run, tmax);
                float corr = __builtin_amdgcn_exp2f(m_run - mnew);
                m_run = mnew;
                float rsum = 0.f;
                #pragma unroll
                for (int kt = 0; kt < 4; ++kt)
                    #pragma unroll
                    for (int r = 0; r < 4; ++r) {
                        float pe = __builtin_amdgcn_exp2f(s_acc[kt][r] - mnew);
                        s_acc[kt][r] = pe;
                        rsum += pe;
                    }
                rsum += __shfl_xor(rsum, 16);
                rsum += __shfl_xor(rsum, 32);
                l_run = l_run * corr + rsum;

                // pack P into A-frags (k-order kappa: f[r]=s[2kf][r], f[r+4]=s[2kf+1][r])
                short8v pa[2];
                #pragma unroll
                for (int kf = 0; kf < 2; ++kf) {
                    uint4v u;
                    u[0] = cvt_pk(s_acc[2 * kf][0],     s_acc[2 * kf][1]);
                    u[1] = cvt_pk(s_acc[2 * kf][2],     s_acc[2 * kf][3]);
                    u[2] = cvt_pk(s_acc[2 * kf + 1][0], s_acc[2 * kf + 1][1]);
                    u[3] = cvt_pk(s_acc[2 * kf + 1][2], s_acc[2 * kf + 1][3]);
                    pa[kf] = __builtin_bit_cast(short8v, u);
                }

                // rescale o_acc: lane's o-rows are q = 4lg+r
                #pragma unroll
                for (int r = 0; r < 4; ++r) {
                    float c = __shfl(corr, 4 * lg + r);
                    #pragma unroll
                    for (int dt = 0; dt < 4; ++dt)
                        o_acc[dt][r] *= c;
                }

                // ---- PV: B-frags from V^T with matching kappa k-order ----
                __builtin_amdgcn_s_setprio(1);
                #pragma unroll
                for (int dt = 0; dt < 4; ++dt) {
                    const char* vrow = (const char*)&V_lds[0][0] + (dt * 16 + lr) * (LDPV * 2);
                    #pragma unroll
                    for (int kf = 0; kf < 2; ++kf) {
                        uint2v lo = *(const uint2v*)(vrow + (kf * 32 + 4 * lg) * 2);
                        uint2v hi = *(const uint2v*)(vrow + (kf * 32 + 16 + 4 * lg) * 2);
                        uint4v u = {lo[0], lo[1], hi[0], hi[1]};
                        short8v vv = __builtin_bit_cast(short8v, u);
                        o_acc[dt] = __builtin_amdgcn_mfma_f32_16x16x32_bf16(
                            pa[kf], vv, o_acc[dt], 0, 0, 0);
                    }
                }
                __builtin_amdgcn_s_setprio(0);
            }
        }

        // ---- epilogue for this q-tile ----
        float lsum = __shfl(l_run, 4 * lg + ((lane >> 4) & 0));  // placeholder avoided below
        #pragma unroll
        for (int r = 0; r < 4; ++r) {
            float ls = __shfl(l_run, 4 * lg + r);
            float inv = 1.0f / ls;
            int qrow = q0 + lg * 4 + r;
            float* op = Og + (size_t)qrow * DH + lr;
            #pragma unroll
            for (int dt = 0; dt < 4; ++dt)
                op[dt * 16] = o_acc[dt][r] * inv;
        }
        (void)lsum;
    }
}

extern "C" void kernel_launch(void* const* d_in, const int* in_sizes, int n_in,
                              void* d_out, int out_size, void* d_ws, size_t ws_size,
                              hipStream_t stream) {
    const float* q = (const float*)d_in[0];
    const float* k = (const float*)d_in[1];
    const float* v = (const float*)d_in[2];
    float* out = (float*)d_out;
    // 512 uniform blocks x 512 threads: 64 (b,h) x 8 q-tile pairs {15-p, p}
    fa_fwd_kernel<<<dim3(512), dim3(512), 0, stream>>>(q, k, v, out);
}

// Round 6
// 79.017 us; speedup vs baseline: 4.2006x; 1.0058x over previous
//
#include <hip/hip_runtime.h>
#include <hip/hip_bf16.h>

#define S_LEN 2048
#define DH 64
#define QBLK 128
#define KVBLK 64
#define LDPK 72   // K rows: 144B (16B-aligned), b128 reads at 8-way = wave64 floor
#define LDPV 68   // V^T rows: 136B (8B-aligned), b64 reads at 4-way = wave64 floor

typedef __attribute__((ext_vector_type(4))) float f32x4;
typedef __attribute__((ext_vector_type(8))) short short8v;
typedef __attribute__((ext_vector_type(4))) unsigned uint4v;
typedef __attribute__((ext_vector_type(2))) unsigned uint2v;

__device__ __forceinline__ unsigned cvt_pk(float a, float b) {
    unsigned r;
    asm("v_cvt_pk_bf16_f32 %0, %1, %2" : "=v"(r) : "v"(a), "v"(b));
    return r;
}

__global__ __launch_bounds__(512) void fa_fwd_kernel(
    const float* __restrict__ Q, const float* __restrict__ K,
    const float* __restrict__ V, float* __restrict__ O)
{
    const int tid  = threadIdx.x;
    const int lane = tid & 63;
    const int w    = tid >> 6;          // 0..7 waves, each owns 16 q-rows
    const int bh   = blockIdx.x & 63;   // same-bh blocks 64 apart -> same XCD
    const int p    = blockIdx.x >> 6;   // uniform pair {15-p, p}: 34 iters/block

    const size_t base = (size_t)bh * S_LEN * DH;
    const float* Qg = Q + base;
    const float* Kg = K + base;
    const float* Vg = V + base;
    float*       Og = O + base;

    // double-buffered K/V tiles: one barrier per KV iteration
    __shared__ __align__(16) short K_lds[2][KVBLK][LDPK];   // [buf][kv][d]
    __shared__ __align__(16) short V_lds[2][DH][LDPV];      // [buf][d][kv]

    const int lr = lane & 15;
    const int lg = lane >> 4;
    // staging decomposition (512 threads cover the 64x64 tile once)
    const int kr = tid >> 3;            // K row 0..63
    const int dc = (tid & 7) * 8;       // K col 0,8,...,56
    const int vd = tid & 63;            // V col (d)
    const int vg = tid >> 6;            // V row-group 0..7

    unsigned kpfu[4], vpf[4];

    auto prefetch = [&](int kvb) {
        const float* kp = Kg + (size_t)(kvb + kr) * DH + dc;
        f32x4 a = *(const f32x4*)kp;
        f32x4 b = *(const f32x4*)(kp + 4);
        kpfu[0] = cvt_pk(a[0], a[1]);
        kpfu[1] = cvt_pk(a[2], a[3]);
        kpfu[2] = cvt_pk(b[0], b[1]);
        kpfu[3] = cvt_pk(b[2], b[3]);
        #pragma unroll
        for (int i = 0; i < 4; ++i) {
            int kv = vg * 8 + i * 2;
            float x = Vg[(size_t)(kvb + kv) * DH + vd];
            float y = Vg[(size_t)(kvb + kv + 1) * DH + vd];
            vpf[i] = cvt_pk(x, y);
        }
    };

    auto stage = [&](int b) {
        uint4v u = {kpfu[0], kpfu[1], kpfu[2], kpfu[3]};
        *(uint4v*)&K_lds[b][kr][dc] = u;                 // ds_write_b128
        #pragma unroll
        for (int i = 0; i < 4; ++i) {
            int kv = vg * 8 + i * 2;
            *(unsigned*)((char*)&V_lds[b][0][0] + vd * (LDPV * 2) + kv * 2) = vpf[i];
        }
    };

    const float qscale = 0.125f * 1.44269504088896340736f;

    prefetch(0);
    stage(0);
    int cur = 0;
    __syncthreads();

    #pragma unroll 1
    for (int t = 0; t < 2; ++t) {
        const int qb = (t == 0) ? (15 - p) : p;   // heavy tile first
        const int q0 = qb * QBLK + w * 16;
        const int kv_end = (qb + 1) * QBLK;

        // ---- Q fragments (scale + log2e folded) ----
        short8v qfrag[2];
        #pragma unroll
        for (int kf = 0; kf < 2; ++kf) {
            const float* qp = Qg + (size_t)(q0 + lr) * DH + kf * 32 + lg * 8;
            f32x4 a = *(const f32x4*)qp;
            f32x4 b = *(const f32x4*)(qp + 4);
            uint4v u;
            u[0] = cvt_pk(a[0] * qscale, a[1] * qscale);
            u[1] = cvt_pk(a[2] * qscale, a[3] * qscale);
            u[2] = cvt_pk(b[0] * qscale, b[1] * qscale);
            u[3] = cvt_pk(b[2] * qscale, b[3] * qscale);
            qfrag[kf] = __builtin_bit_cast(short8v, u);
        }

        f32x4 o_acc[4];
        #pragma unroll
        for (int i = 0; i < 4; ++i)
            o_acc[i] = (f32x4){0.f, 0.f, 0.f, 0.f};
        float m_run = -1e30f, l_run = 0.f;

        #pragma unroll 1
        for (int kvb = 0; kvb < kv_end; kvb += KVBLK) {
            // next tile to prefetch (crosses into second q-tile seamlessly)
            int nkv = kvb + KVBLK;
            bool have = true;
            if (nkv >= kv_end) { if (t == 0) nkv = 0; else have = false; }
            if (have) prefetch(nkv);   // global->reg, lands under compute

            if (kvb <= q0) {   // skip fully-masked diagonal iterations
                const short (*Kc)[LDPK] = K_lds[cur];
                const char* Vc = (const char*)&V_lds[cur][0][0];

                // ---- swapped QK^T: lane holds q=lr, kv=16kt+4lg+r ----
                f32x4 s_acc[4];
                #pragma unroll
                for (int kt = 0; kt < 4; ++kt)
                    s_acc[kt] = (f32x4){0.f, 0.f, 0.f, 0.f};

                __builtin_amdgcn_s_setprio(1);
                #pragma unroll
                for (int kt = 0; kt < 4; ++kt) {
                    short8v kf0 = *(const short8v*)&Kc[kt * 16 + lr][lg * 8];
                    short8v kf1 = *(const short8v*)&Kc[kt * 16 + lr][32 + lg * 8];
                    s_acc[kt] = __builtin_amdgcn_mfma_f32_16x16x32_bf16(
                        kf0, qfrag[0], s_acc[kt], 0, 0, 0);
                    s_acc[kt] = __builtin_amdgcn_mfma_f32_16x16x32_bf16(
                        kf1, qfrag[1], s_acc[kt], 0, 0, 0);
                }
                __builtin_amdgcn_s_setprio(0);

                // ---- mask (diagonal tiles only) ----
                const int qrow = q0 + lr;
                if (kvb + KVBLK - 1 > q0) {
                    #pragma unroll
                    for (int kt = 0; kt < 4; ++kt)
                        #pragma unroll
                        for (int r = 0; r < 4; ++r) {
                            int kvv = kvb + kt * 16 + lg * 4 + r;
                            if (kvv > qrow) s_acc[kt][r] = -1e30f;
                        }
                }

                // ---- online softmax with defer-max (THR=8 in log2 domain) ----
                float tmax = -1e30f;
                #pragma unroll
                for (int kt = 0; kt < 4; ++kt)
                    #pragma unroll
                    for (int r = 0; r < 4; ++r)
                        tmax = fmaxf(tmax, s_acc[kt][r]);
                tmax = fmaxf(tmax, __shfl_xor(tmax, 16));
                tmax = fmaxf(tmax, __shfl_xor(tmax, 32));

                if (!__all(tmax <= m_run + 8.0f)) {
                    float mnew = fmaxf(m_run, tmax);
                    float corr = __builtin_amdgcn_exp2f(m_run - mnew);
                    m_run = mnew;
                    l_run *= corr;
                    #pragma unroll
                    for (int r = 0; r < 4; ++r) {
                        float c = __shfl(corr, 4 * lg + r);
                        #pragma unroll
                        for (int dt = 0; dt < 4; ++dt)
                            o_acc[dt][r] *= c;
                    }
                }

                float rsum = 0.f;
                #pragma unroll
                for (int kt = 0; kt < 4; ++kt)
                    #pragma unroll
                    for (int r = 0; r < 4; ++r) {
                        float pe = __builtin_amdgcn_exp2f(s_acc[kt][r] - m_run);
                        s_acc[kt][r] = pe;
                        rsum += pe;
                    }
                rsum += __shfl_xor(rsum, 16);
                rsum += __shfl_xor(rsum, 32);
                l_run += rsum;

                // pack P into A-frags (k-order kappa: f[r]=s[2kf][r], f[r+4]=s[2kf+1][r])
                short8v pa[2];
                #pragma unroll
                for (int kf = 0; kf < 2; ++kf) {
                    uint4v u;
                    u[0] = cvt_pk(s_acc[2 * kf][0],     s_acc[2 * kf][1]);
                    u[1] = cvt_pk(s_acc[2 * kf][2],     s_acc[2 * kf][3]);
                    u[2] = cvt_pk(s_acc[2 * kf + 1][0], s_acc[2 * kf + 1][1]);
                    u[3] = cvt_pk(s_acc[2 * kf + 1][2], s_acc[2 * kf + 1][3]);
                    pa[kf] = __builtin_bit_cast(short8v, u);
                }

                // ---- PV: B-frags from V^T with matching kappa k-order ----
                __builtin_amdgcn_s_setprio(1);
                #pragma unroll
                for (int dt = 0; dt < 4; ++dt) {
                    const char* vrow = Vc + (dt * 16 + lr) * (LDPV * 2);
                    #pragma unroll
                    for (int kf = 0; kf < 2; ++kf) {
                        uint2v lo = *(const uint2v*)(vrow + (kf * 32 + 4 * lg) * 2);
                        uint2v hi = *(const uint2v*)(vrow + (kf * 32 + 16 + 4 * lg) * 2);
                        uint4v u = {lo[0], lo[1], hi[0], hi[1]};
                        short8v vv = __builtin_bit_cast(short8v, u);
                        o_acc[dt] = __builtin_amdgcn_mfma_f32_16x16x32_bf16(
                            pa[kf], vv, o_acc[dt], 0, 0, 0);
                    }
                }
                __builtin_amdgcn_s_setprio(0);
            }

            // ---- stage next tile into the other buffer; single barrier ----
            if (have) {
                stage(cur ^ 1);
                __syncthreads();
            }
            cur ^= 1;
        }

        // ---- epilogue for this q-tile ----
        #pragma unroll
        for (int r = 0; r < 4; ++r) {
            float ls = __shfl(l_run, 4 * lg + r);
            float inv = 1.0f / ls;
            int qrow = q0 + lg * 4 + r;
            float* op = Og + (size_t)qrow * DH + lr;
            #pragma unroll
            for (int dt = 0; dt < 4; ++dt)
                op[dt * 16] = o_acc[dt][r] * inv;
        }
    }
}

extern "C" void kernel_launch(void* const* d_in, const int* in_sizes, int n_in,
                              void* d_out, int out_size, void* d_ws, size_t ws_size,
                              hipStream_t stream) {
    const float* q = (const float*)d_in[0];
    const float* k = (const float*)d_in[1];
    const float* v = (const float*)d_in[2];
    float* out = (float*)d_out;
    // 512 uniform blocks x 512 threads: 64 (b,h) x 8 q-tile pairs {15-p, p}
    fa_fwd_kernel<<<dim3(512), dim3(512), 0, stream>>>(q, k, v, out);
}